// Round 24
// baseline (306.624 us; speedup 1.0000x reference)
//
#include <hip/hip_runtime.h>
#include <stdint.h>

// ---------- types / helpers ----------
typedef __attribute__((ext_vector_type(4))) float f32x4;
typedef __attribute__((ext_vector_type(8))) __bf16 bf16x8;
typedef __attribute__((ext_vector_type(8))) unsigned short u16x8;
typedef __attribute__((ext_vector_type(4))) unsigned short u16x4;

typedef const __attribute__((address_space(1))) unsigned int gu32;
typedef __attribute__((address_space(3))) unsigned int lu32;

__device__ __forceinline__ float b2f(unsigned short u) {
  unsigned int x = ((unsigned int)u) << 16;
  float f; __builtin_memcpy(&f, &x, 4); return f;
}
__device__ __forceinline__ unsigned short f2b(float f) {
  unsigned int x; __builtin_memcpy(&x, &f, 4);
  x += 0x7fffu + ((x >> 16) & 1u);           // round-to-nearest-even
  return (unsigned short)(x >> 16);
}
__device__ __forceinline__ float sigmoidf(float x) {
  return 1.f / (1.f + __expf(-x));
}
__device__ __forceinline__ float tanh_fast(float x) {
  return 1.f - 2.f / (1.f + __expf(2.f * x));  // exact at +-inf, ~2ulp
}

// ---------- prep part 1: weight transposes + gather (f32 src) ----------
// blocks [0,3200): transpose 4 weights; [3200,7296): gather Xall/ERall.
// Transpose tile swizzle (r17): conflict-free (verified r18: BANK_CONFLICT = 0).
__global__ __launch_bounds__(256) void prep1(
    const float* __restrict__ Wx, unsigned short* __restrict__ WxT,
    const float* __restrict__ Wh, unsigned short* __restrict__ WhT,
    const float* __restrict__ W1, unsigned short* __restrict__ W1T,
    const float* __restrict__ W2, unsigned short* __restrict__ W2T,
    const float* __restrict__ ent, const float* __restrict__ rel,
    const float* __restrict__ rln,
    const int* __restrict__ cur, const int* __restrict__ prl,
    unsigned short* __restrict__ Xall, unsigned short* __restrict__ ERall) {
  __shared__ unsigned short tile[64][72];
  const int tid = threadIdx.x;
  int b = blockIdx.x;
  if (b < 3200) {
    const float* in; unsigned short* out; int R, C, bx, by;
    if (b < 1024)      { in = Wx; out = WxT; R = 1024; C = 4096; bx = b & 63; by = b >> 6; }
    else if (b < 2048) { b -= 1024; in = Wh; out = WhT; R = 1024; C = 4096; bx = b & 63; by = b >> 6; }
    else if (b < 2816) { b -= 2048; in = W1; out = W1T; R = 2048; C = 1536; bx = b % 24; by = b / 24; }
    else               { b -= 2816; in = W2; out = W2T; R = 1536; C = 1024; bx = b & 15; by = b >> 4; }
    const int r0 = by * 64, c0 = bx * 64;
    const int r = tid >> 3;             // 0..31
    const int c8 = (tid & 7) * 8;       // 0..56
#pragma unroll
    for (int i = 0; i < 2; i++) {
      const int rr = r + 32*i;
      const float* src = in + (size_t)(r0 + rr) * C + c0 + c8;
      f32x4 a = *(const f32x4*)src;
      f32x4 bb = *(const f32x4*)(src + 4);
      unsigned short tmp[8];
#pragma unroll
      for (int j = 0; j < 4; j++) { tmp[j] = f2b(a[j]); tmp[4+j] = f2b(bb[j]); }
      *(u16x8*)(&tile[rr][c8 ^ (((rr >> 3) & 7) << 3)]) = *(u16x8*)tmp;
    }
    __syncthreads();
    const int rswz = (tid & 7) << 3;
#pragma unroll
    for (int i = 0; i < 2; i++) {
      const int ro = r + 32*i;
      unsigned short tmp[8];
#pragma unroll
      for (int j = 0; j < 8; j++) tmp[j] = tile[c8 + j][ro ^ rswz];
      *(u16x8*)(out + (size_t)(c0 + ro) * R + r0 + c8) = *(u16x8*)tmp;
    }
  } else {
    const int row = b - 3200;            // t*512 + bb, 0..4095
    const int bb = row & 511;
    const int ci = cur[row], ri = prl[row];
    const int half = tid >> 7;           // 0: Xall, 1: ERall
    const int j = tid & 127;             // chunk of 8 within the 1024-row
    const float* src;
    if (half == 0) src = (j < 64) ? (rel + (size_t)ri * 512 + j * 8)
                                  : (ent + (size_t)ci * 512 + (j - 64) * 8);
    else           src = (j < 64) ? (ent + (size_t)ci * 512 + j * 8)
                                  : (rln + (size_t)bb * 512 + (j - 64) * 8);
    f32x4 a = *(const f32x4*)src, c = *(const f32x4*)(src + 4);
    unsigned short t[8];
#pragma unroll
    for (int q = 0; q < 4; q++) { t[q] = f2b(a[q]); t[4+q] = f2b(c[q]); }
    unsigned short* dst = (half == 0 ? Xall : ERall) + (size_t)row * 1024 + j * 8;
    *(u16x8*)dst = *(u16x8*)t;
  }
}

// ---------- bf16 MFMA GEMM, tile 128x128, 4 waves, GLD + both-sides XOR swizzle ----------
// C = A[M][K] * BT[N][K]^T (+bias f32)(relu).  (r21-proven structure)
// PERM_B: B row n reads physical row (n&3)*1024 + (n>>2)  (gate-interleave of Wx cols)
// ASPLIT: A col k: k<512 -> A[k]; k<1536 -> A2[k-512]; else A[k-1024].
// LSTM0: blocks with m0<512 run the t=0 gate epilogue (c0=0) -> Hout/Cst.
template<bool HAS_BIAS, bool DO_RELU, bool PERM_B, bool ASPLIT, bool LSTM0>
__global__ __launch_bounds__(256) void gemm_bf16(
    const unsigned short* __restrict__ A,
    const unsigned short* __restrict__ A2, int lda,
    const unsigned short* __restrict__ BT, int ldb, int K,
    const float* __restrict__ bias,
    unsigned short* __restrict__ Cout, int ldc,
    const float* __restrict__ gbias,
    unsigned short* __restrict__ Hout, float* __restrict__ Cst) {
  __shared__ unsigned short As[128][64];
  __shared__ unsigned short Bs[128][64];
  const int tid = threadIdx.x;
  const int lane = tid & 63;
  const int w = tid >> 6;
  const int wr = w >> 1, wc = w & 1;                // 2x2 wave grid
  const int m0 = blockIdx.y * 128, n0 = blockIdx.x * 128;
  f32x4 acc[4][4] = {};
  const int srow = lane >> 3;                       // 0..7 within chunk
  const int scol = ((lane & 7) ^ srow) * 8;         // swizzled source col (elems)

  for (int k0 = 0; k0 < K; k0 += 64) {
    const unsigned short* asrc; int ac;
    if (ASPLIT) {
      if (k0 < 512)       { asrc = A;  ac = k0; }
      else if (k0 < 1536) { asrc = A2; ac = k0 - 512; }
      else                { asrc = A;  ac = k0 - 1024; }
    } else { asrc = A; ac = k0; }
#pragma unroll
    for (int i = 0; i < 4; i++) {
      const int c = w * 4 + i;                      // chunk 0..15 (8 rows each)
      const int row = c * 8 + srow;
      __builtin_amdgcn_global_load_lds(
          (gu32*)(asrc + (size_t)(m0 + row) * lda + ac + scol),
          (lu32*)(&As[0][0] + c * 512), 16, 0, 0);
      const int brow = n0 + row;
      const int prow = PERM_B ? (((brow & 3) << 10) + (brow >> 2)) : brow;
      __builtin_amdgcn_global_load_lds(
          (gu32*)(BT + (size_t)prow * ldb + k0 + scol),
          (lu32*)(&Bs[0][0] + c * 512), 16, 0, 0);
    }
    __syncthreads();
#pragma unroll
    for (int ks = 0; ks < 2; ks++) {
      const int kb = ks * 32 + (lane >> 4) * 8;
      const int kswz = kb ^ ((lane & 7) << 3);      // read-side swizzle
      bf16x8 af[4], bfr[4];
#pragma unroll
      for (int m = 0; m < 4; m++)
        af[m] = *reinterpret_cast<const bf16x8*>(&As[wr*64 + m*16 + (lane & 15)][kswz]);
#pragma unroll
      for (int n = 0; n < 4; n++)
        bfr[n] = *reinterpret_cast<const bf16x8*>(&Bs[wc*64 + n*16 + (lane & 15)][kswz]);
#pragma unroll
      for (int m = 0; m < 4; m++)
#pragma unroll
        for (int n = 0; n < 4; n++)
          acc[m][n] = __builtin_amdgcn_mfma_f32_16x16x32_bf16(af[m], bfr[n], acc[m][n], 0, 0, 0);
    }
    __syncthreads();
  }

  // C/D layout: col = lane&15 (n), row = (lane>>4)*4 + r (m)  [verified m89]
  const int cn = lane & 15, rb = (lane >> 4) * 4;
  if (LSTM0 && m0 < 512) {
    // t=0 gate epilogue: z = acc (x0 @ Wx, gate-interleaved cols) + bias; c0 = 0.
    const int g = lane & 3;
#pragma unroll
    for (int m = 0; m < 4; m++) {
#pragma unroll
      for (int n = 0; n < 4; n++) {
        const int gn = n0 + wc*64 + n*16 + cn;       // gn&3 == lane&3 == g
        const int u = gn >> 2;
        const float gb = gbias[g * 1024 + u];
        const int row0 = m0 + wr*64 + m*16 + rb;
        const float v0 = acc[m][n][0] + gb;
        const float v1 = acc[m][n][1] + gb;
        const float v2 = acc[m][n][2] + gb;
        const float v3 = acc[m][n][3] + gb;
        auto sel = [&](int idx) {
          return idx == 0 ? v0 : idx == 1 ? v1 : idx == 2 ? v2 : v3;
        };
        const float own = sel(g);
        const float r1 = __shfl_xor(sel(g ^ 1), 1);
        const float r2 = __shfl_xor(sel(g ^ 2), 2);
        const float r3 = __shfl_xor(sel(g ^ 3), 3);
        const float zi = g==0 ? own : g==1 ? r1 : g==2 ? r2 : r3;
        const float zg_= g==0 ? r2  : g==1 ? r3 : g==2 ? own: r1;
        const float zo = g==0 ? r3  : g==1 ? r2 : g==2 ? r1 : own;
        const float cnew = sigmoidf(zi) * tanh_fast(zg_);   // f-gate * 0 drops
        const float h = sigmoidf(zo) * tanh_fast(cnew);
        const size_t hidx = (size_t)(row0 + g) * 1024 + u;
        Cst[hidx] = cnew;
        Hout[hidx] = f2b(h);
      }
    }
    return;
  }
#pragma unroll
  for (int m = 0; m < 4; m++) {
#pragma unroll
    for (int n = 0; n < 4; n++) {
      const int gn = n0 + wc*64 + n*16 + cn;
#pragma unroll
      for (int r = 0; r < 4; r++) {
        const int gm = m0 + wr*64 + m*16 + rb + r;
        float v = acc[m][n][r];
        if (HAS_BIAS) v += bias[gn];
        if (DO_RELU)  v = v > 0.f ? v : 0.f;
        Cout[(size_t)gm * ldc + gn] = f2b(v);
      }
    }
  }
}

// ---------- fused Z-GEMM + LSTM gate, 64x64 tile, 8 waves, split-K, dbuf GLD ----------
// r21: 2 blocks/CU.  r24: each THREAD also converts 2 table chunks (f32->bf16):
// loads issued at entry (latency hides under the latency-bound chain), stores at
// exit.  7 launches x 512 blk x 512 thr x 2 = 3.67M chunks >= 3.52M needed.
__global__ __launch_bounds__(512) void zgemm_lstm(
    const unsigned short* __restrict__ A,     // Hprev [512][1024]
    const unsigned short* __restrict__ BT,    // WhT [4096][1024]
    const unsigned short* __restrict__ pre,   // P1 slice [512][4096] (perm cols)
    const float* __restrict__ bias,           // [4096] gate-major i,f,g,o
    unsigned short* __restrict__ Hout,        // [512][1024]
    float* __restrict__ Cst,                  // [512][1024]
    const float* __restrict__ entF, unsigned short* __restrict__ entB,
    const float* __restrict__ relF, unsigned short* __restrict__ relB,
    long long conv_base) {                    // chunk offset for this launch
  __shared__ unsigned short As[2][2][64][64];   // [buf][q] 32 KB
  __shared__ unsigned short Bs[2][2][64][64];   // [buf][q] 32 KB
  __shared__ f32x4 accL[4][256];                // 16 KB
  const int tid = threadIdx.x;
  const int lane = tid & 63;
  const int w = tid >> 6;            // 0..7
  const int q = w >> 2;              // K-half
  const int wq = w & 3;              // wave within quad
  const int wr = wq >> 1, wc = wq & 1;
  const int m0 = blockIdx.y * 64, n0 = blockIdx.x * 64;
  f32x4 acc[2][2] = {};
  const int tq = tid & 255;          // thread id within quad
  const int srow = lane >> 3;        // 0..7 within chunk
  const int scol = ((lane & 7) ^ srow) * 8;   // swizzled source col (elems)

  auto STAGE = [&](int buf, int k0) {
    const int kk = q * 512 + k0;
#pragma unroll
    for (int i = 0; i < 2; i++) {
      const int c = wq * 2 + i;                 // chunk 0..7 (8 rows each)
      const int row = c * 8 + srow;
      __builtin_amdgcn_global_load_lds(
          (gu32*)(A + (size_t)(m0 + row) * 1024 + kk + scol),
          (lu32*)(&As[buf][q][0][0] + c * 512), 16, 0, 0);
      const int brow = n0 + row;
      const int prow = ((brow & 3) << 10) + (brow >> 2);
      __builtin_amdgcn_global_load_lds(
          (gu32*)(BT + (size_t)prow * 1024 + kk + scol),
          (lu32*)(&Bs[buf][q][0][0] + c * 512), 16, 0, 0);
    }
  };

  STAGE(0, 0);

  // conv prefetch: 2 chunks of 8 f32 per thread, loads in flight during GEMM
  const long long NC0 = 50000LL * 512 / 8;           // ent chunks
  const long long NC  = NC0 + 5000LL * 512 / 8;      // total chunks
  const long long ci  = conv_base +
      ((long long)(blockIdx.y * 64 + blockIdx.x) * 512 + tid) * 2;
  f32x4 cva0, cvb0, cva1, cvb1;
  const bool cv0 = ci < NC, cv1 = ci + 1 < NC;
  if (cv0) {
    const float* p = (ci < NC0) ? entF + ci * 8 : relF + (ci - NC0) * 8;
    cva0 = *(const f32x4*)p; cvb0 = *(const f32x4*)(p + 4);
  }
  if (cv1) {
    const long long c1 = ci + 1;
    const float* p = (c1 < NC0) ? entF + c1 * 8 : relF + (c1 - NC0) * 8;
    cva1 = *(const f32x4*)p; cvb1 = *(const f32x4*)(p + 4);
  }

  __syncthreads();
  for (int k0 = 0; k0 < 512; k0 += 64) {
    const int buf = (k0 >> 6) & 1;
    if (k0 + 64 < 512) STAGE(buf ^ 1, k0 + 64);
#pragma unroll
    for (int ks = 0; ks < 2; ks++) {
      const int kb = ks * 32 + (lane >> 4) * 8;
      const int kswz = kb ^ ((lane & 7) << 3);  // read-side swizzle
      bf16x8 af[2], bfr[2];
#pragma unroll
      for (int m = 0; m < 2; m++)
        af[m] = *reinterpret_cast<const bf16x8*>(&As[buf][q][wr*32 + m*16 + (lane & 15)][kswz]);
#pragma unroll
      for (int n = 0; n < 2; n++)
        bfr[n] = *reinterpret_cast<const bf16x8*>(&Bs[buf][q][wc*32 + n*16 + (lane & 15)][kswz]);
#pragma unroll
      for (int m = 0; m < 2; m++)
#pragma unroll
        for (int n = 0; n < 2; n++)
          acc[m][n] = __builtin_amdgcn_mfma_f32_16x16x32_bf16(af[m], bfr[n], acc[m][n], 0, 0, 0);
    }
    __syncthreads();
  }

  if (q == 1) {
#pragma unroll
    for (int m = 0; m < 2; m++)
#pragma unroll
      for (int n = 0; n < 2; n++)
        accL[m*2 + n][tq] = acc[m][n];
  }
  __syncthreads();
  if (q == 0) {
    const int cn = lane & 15, rb = (lane >> 4) * 4, g = lane & 3;
#pragma unroll
    for (int m = 0; m < 2; m++) {
#pragma unroll
      for (int n = 0; n < 2; n++) {
        const f32x4 s4 = accL[m*2 + n][tq];
        const int gn = n0 + wc*32 + n*16 + cn;       // gn&3 == lane&3 == g
        const int u = gn >> 2;
        const float gb = bias[g * 1024 + u];
        const int row0 = m0 + wr*32 + m*16 + rb;
        const float v0 = acc[m][n][0] + s4[0] + b2f(pre[(size_t)(row0+0) * 4096 + gn]) + gb;
        const float v1 = acc[m][n][1] + s4[1] + b2f(pre[(size_t)(row0+1) * 4096 + gn]) + gb;
        const float v2 = acc[m][n][2] + s4[2] + b2f(pre[(size_t)(row0+2) * 4096 + gn]) + gb;
        const float v3 = acc[m][n][3] + s4[3] + b2f(pre[(size_t)(row0+3) * 4096 + gn]) + gb;
        auto sel = [&](int idx) {
          return idx == 0 ? v0 : idx == 1 ? v1 : idx == 2 ? v2 : v3;
        };
        const float own = sel(g);
        const float r1 = __shfl_xor(sel(g ^ 1), 1);
        const float r2 = __shfl_xor(sel(g ^ 2), 2);
        const float r3 = __shfl_xor(sel(g ^ 3), 3);
        const float zi = g==0 ? own : g==1 ? r1 : g==2 ? r2 : r3;
        const float zf = g==0 ? r1  : g==1 ? own: g==2 ? r3 : r2;
        const float zg_= g==0 ? r2  : g==1 ? r3 : g==2 ? own: r1;
        const float zo = g==0 ? r3  : g==1 ? r2 : g==2 ? r1 : own;
        const size_t hidx = (size_t)(row0 + g) * 1024 + u;
        const float cnew = sigmoidf(zf) * Cst[hidx] + sigmoidf(zi) * tanh_fast(zg_);
        const float h = sigmoidf(zo) * tanh_fast(cnew);
        Cst[hidx] = cnew;
        Hout[hidx] = f2b(h);
      }
    }
  }

  // conv store (all 512 threads)
  if (cv0) {
    unsigned short* o = (ci < NC0) ? entB + ci * 8 : relB + (ci - NC0) * 8;
    unsigned short t[8];
#pragma unroll
    for (int j = 0; j < 4; j++) { t[j] = f2b(cva0[j]); t[4+j] = f2b(cvb0[j]); }
    *(u16x8*)o = *(u16x8*)t;
  }
  if (cv1) {
    const long long c1 = ci + 1;
    unsigned short* o = (c1 < NC0) ? entB + c1 * 8 : relB + (c1 - NC0) * 8;
    unsigned short t[8];
#pragma unroll
    for (int j = 0; j < 4; j++) { t[j] = f2b(cva1[j]); t[4+j] = f2b(cvb1[j]); }
    *(u16x8*)o = *(u16x8*)t;
  }
}

// ---------- candidate scoring + softmax: one block per (t,b) row (bf16 tables) ----------
__global__ __launch_bounds__(256) void score_softmax(
    const unsigned short* __restrict__ F2,    // [4096][1024] bf16
    const unsigned short* __restrict__ relB,  // [5000][512] bf16
    const unsigned short* __restrict__ entB,  // [50000][512] bf16
    const int* __restrict__ crel, const int* __restrict__ cent, // [4096][32]
    float* __restrict__ outp) {               // [4096][32] f32
  const int b = blockIdx.x;                   // 0..4095
  const int tid = threadIdx.x;
  const int lane = tid & 63, w = tid >> 6;
  __shared__ float feat[1024];
  __shared__ float logits[32];
  {
    u16x4 fv = ((const u16x4*)(F2 + (size_t)b * 1024))[tid];
#pragma unroll
    for (int j = 0; j < 4; j++) feat[tid * 4 + j] = b2f(fv[j]);
  }
  __syncthreads();
  for (int k = w; k < 32; k += 4) {
    const int ri = crel[b * 32 + k], ei = cent[b * 32 + k];
    u16x8 rv = *(const u16x8*)(relB + (size_t)ri * 512 + lane * 8);
    u16x8 ev = *(const u16x8*)(entB + (size_t)ei * 512 + lane * 8);
    float sum = 0.f;
#pragma unroll
    for (int j = 0; j < 8; j++) {
      sum += b2f(rv[j]) * feat[lane * 8 + j];
      sum += b2f(ev[j]) * feat[512 + lane * 8 + j];
    }
#pragma unroll
    for (int off = 32; off; off >>= 1) sum += __shfl_down(sum, off, 64);
    if (lane == 0) logits[k] = sum;
  }
  __syncthreads();
  if (tid < 32) {
    const float l = logits[tid];
    float mx = l;
#pragma unroll
    for (int off = 16; off; off >>= 1) mx = fmaxf(mx, __shfl_xor(mx, off, 32));
    const float p = __expf(l - mx);
    float s = p;
#pragma unroll
    for (int off = 16; off; off >>= 1) s += __shfl_xor(s, off, 32);
    outp[(size_t)b * 32 + tid] = p / s;
  }
}

// ---------- host launch ----------
extern "C" void kernel_launch(void* const* d_in, const int* in_sizes, int n_in,
                              void* d_out, int out_size, void* d_ws, size_t ws_size,
                              hipStream_t stream) {
  const float* ent      = (const float*)d_in[0];  // [50000][512]
  const float* rel      = (const float*)d_in[1];  // [5000][512]
  const float* relation = (const float*)d_in[2];  // [512][512]
  const float* Wx       = (const float*)d_in[3];  // [1024][4096]
  const float* Wh       = (const float*)d_in[4];  // [1024][4096]
  const float* bvec     = (const float*)d_in[5];  // [4096]
  const float* W1       = (const float*)d_in[6];  // [2048][1536]
  const float* b1       = (const float*)d_in[7];  // [1536]
  const float* W2       = (const float*)d_in[8];  // [1536][1024]
  const float* b2       = (const float*)d_in[9];  // [1024]
  const int* cur  = (const int*)d_in[10];  // [8][512]
  const int* prl  = (const int*)d_in[11];  // [8][512]
  const int* crel = (const int*)d_in[12];  // [8][512][32]
  const int* cent = (const int*)d_in[13];  // [8][512][32]
  float* out = (float*)d_out;              // [8][512][32] f32
  (void)in_sizes; (void)n_in; (void)out_size; (void)ws_size;

  char* wsp = (char*)d_ws;
  auto alloc = [&](size_t bytes) { char* p = wsp; wsp += (bytes + 255) & ~(size_t)255; return p; };
  unsigned short* entB = (unsigned short*)alloc((size_t)50000 * 512 * 2); // [50000][512]
  unsigned short* relB = (unsigned short*)alloc((size_t)5000 * 512 * 2);  // [5000][512]
  unsigned short* WxT  = (unsigned short*)alloc((size_t)4096 * 1024 * 2); // [4096][1024]
  unsigned short* WhT  = (unsigned short*)alloc((size_t)4096 * 1024 * 2); // [4096][1024]
  unsigned short* W1T  = (unsigned short*)alloc((size_t)1536 * 2048 * 2); // [1536][2048]
  unsigned short* W2T  = (unsigned short*)alloc((size_t)1024 * 1536 * 2); // [1024][1536]
  unsigned short* Xall = (unsigned short*)alloc((size_t)4096 * 1024 * 2); // [8*512][1024]
  unsigned short* ERall= (unsigned short*)alloc((size_t)4096 * 1024 * 2); // [8*512][1024]
  unsigned short* P1   = (unsigned short*)alloc((size_t)4096 * 4096 * 2); // [8*512][4096] perm cols
  unsigned short* Hall = (unsigned short*)alloc((size_t)4096 * 1024 * 2); // [8*512][1024]
  unsigned short* F1   = (unsigned short*)alloc((size_t)4096 * 1536 * 2); // [8*512][1536]
  unsigned short* F2   = (unsigned short*)alloc((size_t)4096 * 1024 * 2); // [8*512][1024]
  float*          C    = (float*)         alloc((size_t)512 * 1024 * 4);  // [512][1024]

  const dim3 blk(256);
  const size_t HS = (size_t)512 * 1024;    // per-step H elements

  // prep part 1: weight transposes + gather
  prep1<<<7296, blk, 0, stream>>>(
      Wx, WxT, Wh, WhT, W1, W1T, W2, W2T,
      ent, rel, relation, cur, prl, Xall, ERall);

  // P1 = Xall @ Wx (gate-interleaved cols)   [4096,4096] k=1024
  // t=0 block-rows run the fused gate0 epilogue -> Hall[0], C
  gemm_bf16<false,false,true,false,true><<<dim3(32, 32), blk, 0, stream>>>(
      Xall, nullptr, 1024, WxT, 1024, 1024, nullptr, P1, 4096, bvec, Hall, C);

  // sequential LSTM chain (t=1..7), 64x64 2 blocks/CU; each launch also
  // converts 1/7 of the embedding tables via in-thread prefetch (hidden).
  for (int t = 1; t < 8; t++) {
    zgemm_lstm<<<dim3(64, 8), dim3(512), 0, stream>>>(
        Hall + (size_t)(t - 1) * HS, WhT,
        P1 + (size_t)t * 512 * 4096, bvec,
        Hall + (size_t)t * HS, C,
        ent, entB, rel, relB, (long long)(t - 1) * 524288);
  }

  // batched posterior MLP over all 8 steps
  // F1 = relu([ent|h|relation] @ W1 + b1)   [4096,1536] k=2048 (A 3-way split)
  gemm_bf16<true,true,false,true,false><<<dim3(12, 32), blk, 0, stream>>>(
      ERall, Hall, 1024, W1T, 2048, 2048, b1, F1, 1536, nullptr, nullptr, nullptr);
  // F2 = relu(F1 @ W2 + b2)                 [4096,1024] k=1536
  gemm_bf16<true,true,false,false,false><<<dim3(8, 32), blk, 0, stream>>>(
      F1, nullptr, 1536, W2T, 1536, 1536, b2, F2, 1024, nullptr, nullptr, nullptr);

  // candidate scoring + softmax (entB/relB converted during the chain)
  score_softmax<<<4096, 256, 0, stream>>>(F2, relB, entB, crel, cent, out);
}

// Round 25
// 292.536 us; speedup vs baseline: 1.0482x; 1.0482x over previous
//
#include <hip/hip_runtime.h>
#include <stdint.h>

// ---------- types / helpers ----------
typedef __attribute__((ext_vector_type(4))) float f32x4;
typedef __attribute__((ext_vector_type(8))) __bf16 bf16x8;
typedef __attribute__((ext_vector_type(8))) unsigned short u16x8;
typedef __attribute__((ext_vector_type(4))) unsigned short u16x4;

typedef const __attribute__((address_space(1))) unsigned int gu32;
typedef __attribute__((address_space(3))) unsigned int lu32;

__device__ __forceinline__ float b2f(unsigned short u) {
  unsigned int x = ((unsigned int)u) << 16;
  float f; __builtin_memcpy(&f, &x, 4); return f;
}
__device__ __forceinline__ unsigned short f2b(float f) {
  unsigned int x; __builtin_memcpy(&x, &f, 4);
  x += 0x7fffu + ((x >> 16) & 1u);           // round-to-nearest-even
  return (unsigned short)(x >> 16);
}
__device__ __forceinline__ float sigmoidf(float x) {
  return 1.f / (1.f + __expf(-x));
}
__device__ __forceinline__ float tanh_fast(float x) {
  return 1.f - 2.f / (1.f + __expf(2.f * x));  // exact at +-inf, ~2ulp
}

// ---------- prep part 1: weight transposes + gather (f32 src) ----------
// blocks [0,3200): transpose 4 weights; [3200,7296): gather Xall/ERall.
// Transpose tile swizzle (r17): conflict-free (verified r18: BANK_CONFLICT = 0).
__global__ __launch_bounds__(256) void prep1(
    const float* __restrict__ Wx, unsigned short* __restrict__ WxT,
    const float* __restrict__ Wh, unsigned short* __restrict__ WhT,
    const float* __restrict__ W1, unsigned short* __restrict__ W1T,
    const float* __restrict__ W2, unsigned short* __restrict__ W2T,
    const float* __restrict__ ent, const float* __restrict__ rel,
    const float* __restrict__ rln,
    const int* __restrict__ cur, const int* __restrict__ prl,
    unsigned short* __restrict__ Xall, unsigned short* __restrict__ ERall) {
  __shared__ unsigned short tile[64][72];
  const int tid = threadIdx.x;
  int b = blockIdx.x;
  if (b < 3200) {
    const float* in; unsigned short* out; int R, C, bx, by;
    if (b < 1024)      { in = Wx; out = WxT; R = 1024; C = 4096; bx = b & 63; by = b >> 6; }
    else if (b < 2048) { b -= 1024; in = Wh; out = WhT; R = 1024; C = 4096; bx = b & 63; by = b >> 6; }
    else if (b < 2816) { b -= 2048; in = W1; out = W1T; R = 2048; C = 1536; bx = b % 24; by = b / 24; }
    else               { b -= 2816; in = W2; out = W2T; R = 1536; C = 1024; bx = b & 15; by = b >> 4; }
    const int r0 = by * 64, c0 = bx * 64;
    const int r = tid >> 3;             // 0..31
    const int c8 = (tid & 7) * 8;       // 0..56
#pragma unroll
    for (int i = 0; i < 2; i++) {
      const int rr = r + 32*i;
      const float* src = in + (size_t)(r0 + rr) * C + c0 + c8;
      f32x4 a = *(const f32x4*)src;
      f32x4 bb = *(const f32x4*)(src + 4);
      unsigned short tmp[8];
#pragma unroll
      for (int j = 0; j < 4; j++) { tmp[j] = f2b(a[j]); tmp[4+j] = f2b(bb[j]); }
      *(u16x8*)(&tile[rr][c8 ^ (((rr >> 3) & 7) << 3)]) = *(u16x8*)tmp;
    }
    __syncthreads();
    const int rswz = (tid & 7) << 3;
#pragma unroll
    for (int i = 0; i < 2; i++) {
      const int ro = r + 32*i;
      unsigned short tmp[8];
#pragma unroll
      for (int j = 0; j < 8; j++) tmp[j] = tile[c8 + j][ro ^ rswz];
      *(u16x8*)(out + (size_t)(c0 + ro) * R + r0 + c8) = *(u16x8*)tmp;
    }
  } else {
    const int row = b - 3200;            // t*512 + bb, 0..4095
    const int bb = row & 511;
    const int ci = cur[row], ri = prl[row];
    const int half = tid >> 7;           // 0: Xall, 1: ERall
    const int j = tid & 127;             // chunk of 8 within the 1024-row
    const float* src;
    if (half == 0) src = (j < 64) ? (rel + (size_t)ri * 512 + j * 8)
                                  : (ent + (size_t)ci * 512 + (j - 64) * 8);
    else           src = (j < 64) ? (ent + (size_t)ci * 512 + j * 8)
                                  : (rln + (size_t)bb * 512 + (j - 64) * 8);
    f32x4 a = *(const f32x4*)src, c = *(const f32x4*)(src + 4);
    unsigned short t[8];
#pragma unroll
    for (int q = 0; q < 4; q++) { t[q] = f2b(a[q]); t[4+q] = f2b(c[q]); }
    unsigned short* dst = (half == 0 ? Xall : ERall) + (size_t)row * 1024 + j * 8;
    *(u16x8*)dst = *(u16x8*)t;
  }
}

// ---------- bf16 MFMA GEMM, tile 128x128, 4 waves, GLD + both-sides XOR swizzle ----------
// C = A[M][K] * BT[N][K]^T (+bias f32)(relu).
// PERM_B: B row n reads physical row (n&3)*1024 + (n>>2)  (gate-interleave of Wx cols)
// ASPLIT: A col k: k<512 -> A[k]; k<1536 -> A2[k-512]; else A[k-1024].
// LSTM0: blocks with m0<512 run the t=0 gate epilogue (c0=0) -> Hout/Cst.
// FUSE_CONV: blocks with blockIdx.y >= 32 instead run f32->bf16 table convert.
//   r25: hosted by P1 (1024 compute blocks, low BW demand) -- r23's F1 host
//   showed contention (65 us vs 62 serial); P1 has ~5 TB/s headroom.
template<bool HAS_BIAS, bool DO_RELU, bool PERM_B, bool ASPLIT, bool LSTM0, bool FUSE_CONV>
__global__ __launch_bounds__(256) void gemm_bf16(
    const unsigned short* __restrict__ A,
    const unsigned short* __restrict__ A2, int lda,
    const unsigned short* __restrict__ BT, int ldb, int K,
    const float* __restrict__ bias,
    unsigned short* __restrict__ Cout, int ldc,
    const float* __restrict__ gbias,
    unsigned short* __restrict__ Hout, float* __restrict__ Cst,
    const float* __restrict__ entF, unsigned short* __restrict__ entB,
    const float* __restrict__ relF, unsigned short* __restrict__ relB) {
  __shared__ unsigned short As[128][64];
  __shared__ unsigned short Bs[128][64];
  const int tid = threadIdx.x;
  if (FUSE_CONV && blockIdx.y >= 32) {
    // ---- bulk f32 -> bf16 convert of ent/rel embedding tables ----
    const long long N0 = 50000LL * 512 / 8, N1 = 5000LL * 512 / 8;
    long long i = ((long long)(blockIdx.y - 32) * gridDim.x + blockIdx.x) * 256 + tid;
    if (i >= N0 + N1) return;
    const float* in; unsigned short* out;
    if (i < N0) { in = entF; out = entB; }
    else        { in = relF; out = relB; i -= N0; }
    f32x4 a = *(const f32x4*)(in + i * 8);
    f32x4 c = *(const f32x4*)(in + i * 8 + 4);
    unsigned short t[8];
#pragma unroll
    for (int q = 0; q < 4; q++) { t[q] = f2b(a[q]); t[4+q] = f2b(c[q]); }
    *(u16x8*)(out + i * 8) = *(u16x8*)t;
    return;
  }
  const int lane = tid & 63;
  const int w = tid >> 6;
  const int wr = w >> 1, wc = w & 1;                // 2x2 wave grid
  const int m0 = blockIdx.y * 128, n0 = blockIdx.x * 128;
  f32x4 acc[4][4] = {};
  const int srow = lane >> 3;                       // 0..7 within chunk
  const int scol = ((lane & 7) ^ srow) * 8;         // swizzled source col (elems)

  for (int k0 = 0; k0 < K; k0 += 64) {
    const unsigned short* asrc; int ac;
    if (ASPLIT) {
      if (k0 < 512)       { asrc = A;  ac = k0; }
      else if (k0 < 1536) { asrc = A2; ac = k0 - 512; }
      else                { asrc = A;  ac = k0 - 1024; }
    } else { asrc = A; ac = k0; }
#pragma unroll
    for (int i = 0; i < 4; i++) {
      const int c = w * 4 + i;                      // chunk 0..15 (8 rows each)
      const int row = c * 8 + srow;
      __builtin_amdgcn_global_load_lds(
          (gu32*)(asrc + (size_t)(m0 + row) * lda + ac + scol),
          (lu32*)(&As[0][0] + c * 512), 16, 0, 0);
      const int brow = n0 + row;
      const int prow = PERM_B ? (((brow & 3) << 10) + (brow >> 2)) : brow;
      __builtin_amdgcn_global_load_lds(
          (gu32*)(BT + (size_t)prow * ldb + k0 + scol),
          (lu32*)(&Bs[0][0] + c * 512), 16, 0, 0);
    }
    __syncthreads();
#pragma unroll
    for (int ks = 0; ks < 2; ks++) {
      const int kb = ks * 32 + (lane >> 4) * 8;
      const int kswz = kb ^ ((lane & 7) << 3);      // read-side swizzle
      bf16x8 af[4], bfr[4];
#pragma unroll
      for (int m = 0; m < 4; m++)
        af[m] = *reinterpret_cast<const bf16x8*>(&As[wr*64 + m*16 + (lane & 15)][kswz]);
#pragma unroll
      for (int n = 0; n < 4; n++)
        bfr[n] = *reinterpret_cast<const bf16x8*>(&Bs[wc*64 + n*16 + (lane & 15)][kswz]);
#pragma unroll
      for (int m = 0; m < 4; m++)
#pragma unroll
        for (int n = 0; n < 4; n++)
          acc[m][n] = __builtin_amdgcn_mfma_f32_16x16x32_bf16(af[m], bfr[n], acc[m][n], 0, 0, 0);
    }
    __syncthreads();
  }

  // C/D layout: col = lane&15 (n), row = (lane>>4)*4 + r (m)  [verified m89]
  const int cn = lane & 15, rb = (lane >> 4) * 4;
  if (LSTM0 && m0 < 512) {
    // t=0 gate epilogue: z = acc (x0 @ Wx, gate-interleaved cols) + bias; c0 = 0.
    const int g = lane & 3;
#pragma unroll
    for (int m = 0; m < 4; m++) {
#pragma unroll
      for (int n = 0; n < 4; n++) {
        const int gn = n0 + wc*64 + n*16 + cn;       // gn&3 == lane&3 == g
        const int u = gn >> 2;
        const float gb = gbias[g * 1024 + u];
        const int row0 = m0 + wr*64 + m*16 + rb;
        const float v0 = acc[m][n][0] + gb;
        const float v1 = acc[m][n][1] + gb;
        const float v2 = acc[m][n][2] + gb;
        const float v3 = acc[m][n][3] + gb;
        auto sel = [&](int idx) {
          return idx == 0 ? v0 : idx == 1 ? v1 : idx == 2 ? v2 : v3;
        };
        const float own = sel(g);
        const float r1 = __shfl_xor(sel(g ^ 1), 1);
        const float r2 = __shfl_xor(sel(g ^ 2), 2);
        const float r3 = __shfl_xor(sel(g ^ 3), 3);
        const float zi = g==0 ? own : g==1 ? r1 : g==2 ? r2 : r3;
        const float zg_= g==0 ? r2  : g==1 ? r3 : g==2 ? own: r1;
        const float zo = g==0 ? r3  : g==1 ? r2 : g==2 ? r1 : own;
        const float cnew = sigmoidf(zi) * tanh_fast(zg_);   // f-gate * 0 drops
        const float h = sigmoidf(zo) * tanh_fast(cnew);
        const size_t hidx = (size_t)(row0 + g) * 1024 + u;
        Cst[hidx] = cnew;
        Hout[hidx] = f2b(h);
      }
    }
    return;
  }
#pragma unroll
  for (int m = 0; m < 4; m++) {
#pragma unroll
    for (int n = 0; n < 4; n++) {
      const int gn = n0 + wc*64 + n*16 + cn;
#pragma unroll
      for (int r = 0; r < 4; r++) {
        const int gm = m0 + wr*64 + m*16 + rb + r;
        float v = acc[m][n][r];
        if (HAS_BIAS) v += bias[gn];
        if (DO_RELU)  v = v > 0.f ? v : 0.f;
        Cout[(size_t)gm * ldc + gn] = f2b(v);
      }
    }
  }
}

// ---------- fused Z-GEMM + LSTM gate, 64x64 tile, 8 waves, split-K, dbuf GLD ----------
// r21: 2 blocks/CU (4 waves/SIMD).  (r24's in-thread conv prefetch REVERTED:
// the vmcnt(0) drain at each barrier waited on the conv loads too -- +11 us.)
__global__ __launch_bounds__(512) void zgemm_lstm(
    const unsigned short* __restrict__ A,     // Hprev [512][1024]
    const unsigned short* __restrict__ BT,    // WhT [4096][1024]
    const unsigned short* __restrict__ pre,   // P1 slice [512][4096] (perm cols)
    const float* __restrict__ bias,           // [4096] gate-major i,f,g,o
    unsigned short* __restrict__ Hout,        // [512][1024]
    float* __restrict__ Cst) {                // [512][1024]
  __shared__ unsigned short As[2][2][64][64];   // [buf][q] 32 KB
  __shared__ unsigned short Bs[2][2][64][64];   // [buf][q] 32 KB
  __shared__ f32x4 accL[4][256];                // 16 KB
  const int tid = threadIdx.x;
  const int lane = tid & 63;
  const int w = tid >> 6;            // 0..7
  const int q = w >> 2;              // K-half
  const int wq = w & 3;              // wave within quad
  const int wr = wq >> 1, wc = wq & 1;
  const int m0 = blockIdx.y * 64, n0 = blockIdx.x * 64;
  f32x4 acc[2][2] = {};
  const int tq = tid & 255;          // thread id within quad
  const int srow = lane >> 3;        // 0..7 within chunk
  const int scol = ((lane & 7) ^ srow) * 8;   // swizzled source col (elems)

  auto STAGE = [&](int buf, int k0) {
    const int kk = q * 512 + k0;
#pragma unroll
    for (int i = 0; i < 2; i++) {
      const int c = wq * 2 + i;                 // chunk 0..7 (8 rows each)
      const int row = c * 8 + srow;
      __builtin_amdgcn_global_load_lds(
          (gu32*)(A + (size_t)(m0 + row) * 1024 + kk + scol),
          (lu32*)(&As[buf][q][0][0] + c * 512), 16, 0, 0);
      const int brow = n0 + row;
      const int prow = ((brow & 3) << 10) + (brow >> 2);
      __builtin_amdgcn_global_load_lds(
          (gu32*)(BT + (size_t)prow * 1024 + kk + scol),
          (lu32*)(&Bs[buf][q][0][0] + c * 512), 16, 0, 0);
    }
  };

  STAGE(0, 0);
  __syncthreads();
  for (int k0 = 0; k0 < 512; k0 += 64) {
    const int buf = (k0 >> 6) & 1;
    if (k0 + 64 < 512) STAGE(buf ^ 1, k0 + 64);
#pragma unroll
    for (int ks = 0; ks < 2; ks++) {
      const int kb = ks * 32 + (lane >> 4) * 8;
      const int kswz = kb ^ ((lane & 7) << 3);  // read-side swizzle
      bf16x8 af[2], bfr[2];
#pragma unroll
      for (int m = 0; m < 2; m++)
        af[m] = *reinterpret_cast<const bf16x8*>(&As[buf][q][wr*32 + m*16 + (lane & 15)][kswz]);
#pragma unroll
      for (int n = 0; n < 2; n++)
        bfr[n] = *reinterpret_cast<const bf16x8*>(&Bs[buf][q][wc*32 + n*16 + (lane & 15)][kswz]);
#pragma unroll
      for (int m = 0; m < 2; m++)
#pragma unroll
        for (int n = 0; n < 2; n++)
          acc[m][n] = __builtin_amdgcn_mfma_f32_16x16x32_bf16(af[m], bfr[n], acc[m][n], 0, 0, 0);
    }
    __syncthreads();
  }

  if (q == 1) {
#pragma unroll
    for (int m = 0; m < 2; m++)
#pragma unroll
      for (int n = 0; n < 2; n++)
        accL[m*2 + n][tq] = acc[m][n];
  }
  __syncthreads();
  if (q == 0) {
    const int cn = lane & 15, rb = (lane >> 4) * 4, g = lane & 3;
#pragma unroll
    for (int m = 0; m < 2; m++) {
#pragma unroll
      for (int n = 0; n < 2; n++) {
        const f32x4 s4 = accL[m*2 + n][tq];
        const int gn = n0 + wc*32 + n*16 + cn;       // gn&3 == lane&3 == g
        const int u = gn >> 2;
        const float gb = bias[g * 1024 + u];
        const int row0 = m0 + wr*32 + m*16 + rb;
        const float v0 = acc[m][n][0] + s4[0] + b2f(pre[(size_t)(row0+0) * 4096 + gn]) + gb;
        const float v1 = acc[m][n][1] + s4[1] + b2f(pre[(size_t)(row0+1) * 4096 + gn]) + gb;
        const float v2 = acc[m][n][2] + s4[2] + b2f(pre[(size_t)(row0+2) * 4096 + gn]) + gb;
        const float v3 = acc[m][n][3] + s4[3] + b2f(pre[(size_t)(row0+3) * 4096 + gn]) + gb;
        auto sel = [&](int idx) {
          return idx == 0 ? v0 : idx == 1 ? v1 : idx == 2 ? v2 : v3;
        };
        const float own = sel(g);
        const float r1 = __shfl_xor(sel(g ^ 1), 1);
        const float r2 = __shfl_xor(sel(g ^ 2), 2);
        const float r3 = __shfl_xor(sel(g ^ 3), 3);
        const float zi = g==0 ? own : g==1 ? r1 : g==2 ? r2 : r3;
        const float zf = g==0 ? r1  : g==1 ? own: g==2 ? r3 : r2;
        const float zg_= g==0 ? r2  : g==1 ? r3 : g==2 ? own: r1;
        const float zo = g==0 ? r3  : g==1 ? r2 : g==2 ? r1 : own;
        const size_t hidx = (size_t)(row0 + g) * 1024 + u;
        const float cnew = sigmoidf(zf) * Cst[hidx] + sigmoidf(zi) * tanh_fast(zg_);
        const float h = sigmoidf(zo) * tanh_fast(cnew);
        Cst[hidx] = cnew;
        Hout[hidx] = f2b(h);
      }
    }
  }
}

// ---------- candidate scoring + softmax: one block per (t,b) row (bf16 tables) ----------
__global__ __launch_bounds__(256) void score_softmax(
    const unsigned short* __restrict__ F2,    // [4096][1024] bf16
    const unsigned short* __restrict__ relB,  // [5000][512] bf16
    const unsigned short* __restrict__ entB,  // [50000][512] bf16
    const int* __restrict__ crel, const int* __restrict__ cent, // [4096][32]
    float* __restrict__ outp) {               // [4096][32] f32
  const int b = blockIdx.x;                   // 0..4095
  const int tid = threadIdx.x;
  const int lane = tid & 63, w = tid >> 6;
  __shared__ float feat[1024];
  __shared__ float logits[32];
  {
    u16x4 fv = ((const u16x4*)(F2 + (size_t)b * 1024))[tid];
#pragma unroll
    for (int j = 0; j < 4; j++) feat[tid * 4 + j] = b2f(fv[j]);
  }
  __syncthreads();
  for (int k = w; k < 32; k += 4) {
    const int ri = crel[b * 32 + k], ei = cent[b * 32 + k];
    u16x8 rv = *(const u16x8*)(relB + (size_t)ri * 512 + lane * 8);
    u16x8 ev = *(const u16x8*)(entB + (size_t)ei * 512 + lane * 8);
    float sum = 0.f;
#pragma unroll
    for (int j = 0; j < 8; j++) {
      sum += b2f(rv[j]) * feat[lane * 8 + j];
      sum += b2f(ev[j]) * feat[512 + lane * 8 + j];
    }
#pragma unroll
    for (int off = 32; off; off >>= 1) sum += __shfl_down(sum, off, 64);
    if (lane == 0) logits[k] = sum;
  }
  __syncthreads();
  if (tid < 32) {
    const float l = logits[tid];
    float mx = l;
#pragma unroll
    for (int off = 16; off; off >>= 1) mx = fmaxf(mx, __shfl_xor(mx, off, 32));
    const float p = __expf(l - mx);
    float s = p;
#pragma unroll
    for (int off = 16; off; off >>= 1) s += __shfl_xor(s, off, 32);
    outp[(size_t)b * 32 + tid] = p / s;
  }
}

// ---------- host launch ----------
extern "C" void kernel_launch(void* const* d_in, const int* in_sizes, int n_in,
                              void* d_out, int out_size, void* d_ws, size_t ws_size,
                              hipStream_t stream) {
  const float* ent      = (const float*)d_in[0];  // [50000][512]
  const float* rel      = (const float*)d_in[1];  // [5000][512]
  const float* relation = (const float*)d_in[2];  // [512][512]
  const float* Wx       = (const float*)d_in[3];  // [1024][4096]
  const float* Wh       = (const float*)d_in[4];  // [1024][4096]
  const float* bvec     = (const float*)d_in[5];  // [4096]
  const float* W1       = (const float*)d_in[6];  // [2048][1536]
  const float* b1       = (const float*)d_in[7];  // [1536]
  const float* W2       = (const float*)d_in[8];  // [1536][1024]
  const float* b2       = (const float*)d_in[9];  // [1024]
  const int* cur  = (const int*)d_in[10];  // [8][512]
  const int* prl  = (const int*)d_in[11];  // [8][512]
  const int* crel = (const int*)d_in[12];  // [8][512][32]
  const int* cent = (const int*)d_in[13];  // [8][512][32]
  float* out = (float*)d_out;              // [8][512][32] f32
  (void)in_sizes; (void)n_in; (void)out_size; (void)ws_size;

  char* wsp = (char*)d_ws;
  auto alloc = [&](size_t bytes) { char* p = wsp; wsp += (bytes + 255) & ~(size_t)255; return p; };
  unsigned short* entB = (unsigned short*)alloc((size_t)50000 * 512 * 2); // [50000][512]
  unsigned short* relB = (unsigned short*)alloc((size_t)5000 * 512 * 2);  // [5000][512]
  unsigned short* WxT  = (unsigned short*)alloc((size_t)4096 * 1024 * 2); // [4096][1024]
  unsigned short* WhT  = (unsigned short*)alloc((size_t)4096 * 1024 * 2); // [4096][1024]
  unsigned short* W1T  = (unsigned short*)alloc((size_t)1536 * 2048 * 2); // [1536][2048]
  unsigned short* W2T  = (unsigned short*)alloc((size_t)1024 * 1536 * 2); // [1024][1536]
  unsigned short* Xall = (unsigned short*)alloc((size_t)4096 * 1024 * 2); // [8*512][1024]
  unsigned short* ERall= (unsigned short*)alloc((size_t)4096 * 1024 * 2); // [8*512][1024]
  unsigned short* P1   = (unsigned short*)alloc((size_t)4096 * 4096 * 2); // [8*512][4096] perm cols
  unsigned short* Hall = (unsigned short*)alloc((size_t)4096 * 1024 * 2); // [8*512][1024]
  unsigned short* F1   = (unsigned short*)alloc((size_t)4096 * 1536 * 2); // [8*512][1536]
  unsigned short* F2   = (unsigned short*)alloc((size_t)4096 * 1024 * 2); // [8*512][1024]
  float*          C    = (float*)         alloc((size_t)512 * 1024 * 4);  // [512][1024]

  const dim3 blk(256);
  const size_t HS = (size_t)512 * 1024;    // per-step H elements

  // prep part 1: weight transposes + gather
  prep1<<<7296, blk, 0, stream>>>(
      Wx, WxT, Wh, WhT, W1, W1T, W2, W2T,
      ent, rel, relation, cur, prl, Xall, ERall);

  // P1 = Xall @ Wx (gate-interleaved cols)   [4096,4096] k=1024
  // t=0 block-rows run the fused gate0 epilogue -> Hall[0], C.
  // FUSED with the table convert (blocks y>=32; 430 rows x 32 x 256 thr = 3.52M chunks):
  // P1's low BW demand (~0.8 TB/s) absorbs conv's 170 MB nearly free.
  gemm_bf16<false,false,true,false,true,true><<<dim3(32, 32 + 430), blk, 0, stream>>>(
      Xall, nullptr, 1024, WxT, 1024, 1024, nullptr, P1, 4096, bvec, Hall, C,
      ent, entB, rel, relB);

  // sequential LSTM chain: fused Z-GEMM+gate per step (t=1..7), 64x64 2 blocks/CU
  for (int t = 1; t < 8; t++) {
    zgemm_lstm<<<dim3(64, 8), dim3(512), 0, stream>>>(
        Hall + (size_t)(t - 1) * HS, WhT,
        P1 + (size_t)t * 512 * 4096, bvec,
        Hall + (size_t)t * HS, C);
  }

  // batched posterior MLP over all 8 steps
  // F1 = relu([ent|h|relation] @ W1 + b1)   [4096,1536] k=2048 (A 3-way split)
  gemm_bf16<true,true,false,true,false,false><<<dim3(12, 32), blk, 0, stream>>>(
      ERall, Hall, 1024, W1T, 2048, 2048, b1, F1, 1536, nullptr, nullptr, nullptr,
      nullptr, nullptr, nullptr, nullptr);
  // F2 = relu(F1 @ W2 + b2)                 [4096,1024] k=1536
  gemm_bf16<true,true,false,false,false,false><<<dim3(8, 32), blk, 0, stream>>>(
      F1, nullptr, 1536, W2T, 1536, 1536, b2, F2, 1024, nullptr, nullptr, nullptr,
      nullptr, nullptr, nullptr, nullptr);

  // candidate scoring + softmax (entB/relB converted during P1)
  score_softmax<<<4096, 256, 0, stream>>>(F2, relB, entB, crel, cent, out);
}